// Round 10
// baseline (61.059 us; speedup 1.0000x reference)
//
#include <hip/hip_runtime.h>
#include <hip/hip_bf16.h>

// Problem constants
#define BATCH   4096
#define NF      128    // n features == n models
#define NA      16
#define IN_DIM  144    // N_FEATURES + N_ACTIONS
#define KP      160    // w1t K padded to multiple of 32 (col 144 carries b1)
#define KF      192    // fab K padded so row = 384 B (XOR-swizzle closed)
#define HID     256

typedef __attribute__((ext_vector_type(8))) short bf16x8;
typedef __attribute__((ext_vector_type(4))) float f32x4;
typedef unsigned int u32;

// async global->LDS, 16B per lane. LDS dest must be wave-uniform base + lane*16.
__device__ __forceinline__ void gl_lds16(const void* gsrc, void* ldst) {
    __builtin_amdgcn_global_load_lds(
        (const __attribute__((address_space(1))) u32*)gsrc,
        (__attribute__((address_space(3))) u32*)ldst, 16, 0, 0);
}

// ---------------------------------------------------------------------------
// Merged convert kernel:
//   blocks [0, 1280):      W1 [128][144][256] fp32 -> w1t [128][256][160] bf16
//                          (transposed, col 144 := b1 -> GEMM adds bias)
//   blocks [1280, 1664):   fa = concat(f_t, a_t, 1.0, 0pad) -> bf16 [4096][192],
//                          pre-swizzled: chunk cc stored at cc ^ (row&7)
__global__ void convert_all(const float* __restrict__ W1,
                            const float* __restrict__ b1,
                            const float* __restrict__ f_t,
                            const float* __restrict__ a_t,
                            __hip_bfloat16* __restrict__ w1t,
                            __hip_bfloat16* __restrict__ fab) {
    const int bid = blockIdx.x;
    const int t = threadIdx.x;
    if (bid < 1280) {
        __shared__ float tile[16][HID];
        int m = bid / 10;
        int kc = bid - m * 10;
        int k0 = kc * 16;
        if (kc < 9) {
#pragma unroll
            for (int i = 0; i < 16; ++i)
                tile[i][t] = W1[((size_t)m * IN_DIM + (k0 + i)) * HID + t];
            __syncthreads();
            union { ushort us[16]; uint4 q[2]; } pk;
#pragma unroll
            for (int i = 0; i < 16; ++i) {
                __hip_bfloat16 h = __float2bfloat16(tile[i][t]);
                pk.us[i] = *(ushort*)&h;
            }
            uint4* dst = (uint4*)(w1t + ((size_t)m * HID + t) * KP + k0);
            dst[0] = pk.q[0];
            dst[1] = pk.q[1];
        } else {
            // pad region k = 144..159: k=144 carries b1, rest zero.
            union { ushort us[8]; uint4 q; } pk;
#pragma unroll
            for (int j = 0; j < 8; ++j) pk.us[j] = 0;
            __hip_bfloat16 hb = __float2bfloat16(b1[(size_t)m * HID + t]);
            pk.us[0] = *(ushort*)&hb;
            uint4 z = {0u, 0u, 0u, 0u};
            uint4* dst = (uint4*)(w1t + ((size_t)m * HID + t) * KP + IN_DIM);
            dst[0] = pk.q;
            dst[1] = z;
        }
    } else {
        int c = (bid - 1280) * 256 + t;
        const int total = BATCH * (KF / 8);   // 24 chunks per row
        if (c >= total) return;
        int row = c / 24;
        int cc = c - row * 24;
        union { ushort us[8]; uint4 q; } pk;
#pragma unroll
        for (int j = 0; j < 8; ++j) {
            int k = cc * 8 + j;
            float v;
            if (k < NF)            v = f_t[(size_t)row * NF + k];
            else if (k < IN_DIM)   v = a_t[(size_t)row * NA + (k - NF)];
            else if (k == IN_DIM)  v = 1.0f;   // bias lane
            else                   v = 0.0f;
            __hip_bfloat16 h = __float2bfloat16(v);
            pk.us[j] = *(ushort*)&h;
        }
        int pc = cc ^ (row & 7);              // bijective within 24 chunks
        *(uint4*)(fab + (size_t)row * KF + pc * 8) = pk.q;
    }
}

// ---------------------------------------------------------------------------
// Fused grouped MLP, swapped-operand layer-1 MFMA.
// Grid 1024 = 128 m (bid&127) x 8 slices (bid>>7) of 512 rows; 16 tiles of
// 32 rows. 256 thr = 4 waves; wave w owns hid cols [w*64, w*64+64) -> each
// a-frag ds_read feeds 4 MFMAs (hi reuse), 2560 ds_read_b128/CU total.
// ~155 regs -> 3 blocks/CU (12 waves, launch_bounds(256,3)).
// acc zero-init via constant-C first MFMA (no per-tile accvgpr writes).
__global__ __launch_bounds__(256, 3) void fused_mlp(
        const __hip_bfloat16* __restrict__ fab,
        const __hip_bfloat16* __restrict__ w1t,
        const float* __restrict__ W2,
        const float* __restrict__ b2,
        const float* __restrict__ f_t,
        float* __restrict__ out) {
    __shared__ __align__(16) __hip_bfloat16 Abuf[2][32 * KF];  // 2 x 12 KB
    __shared__ __align__(16) float partial[2][4][32];          // 1 KB

    const int bid = blockIdx.x;
    const int m     = bid & 127;     // same-m blocks 128 apart -> same XCD L2
    const int slice = bid >> 7;      // 0..7, 512 rows each
    const int row_base = slice * 512;
    const int t = threadIdx.x;
    const int w = t >> 6;            // wave = hid col group 0..3 (64 cols)
    const int lane = t & 63;
    const int lrow = lane & 15;
    const int g = lane >> 4;         // 0..3
    const int xr = (lrow & 7) << 4;  // byte XOR for swizzled LDS reads

    // ---- prologue: W1T frags (MFMA A operand), W2 per-lane f32x4.
    bf16x8 bfrag[4][5];
#pragma unroll
    for (int hi = 0; hi < 4; ++hi) {
        const int col = w * 64 + hi * 16 + lrow;
        const __hip_bfloat16* wp = w1t + ((size_t)m * HID + col) * KP + g * 8;
#pragma unroll
        for (int ks = 0; ks < 5; ++ks)
            bfrag[hi][ks] = *(const bf16x8*)(wp + ks * 32);
    }
    f32x4 w2v[4];
#pragma unroll
    for (int hi = 0; hi < 4; ++hi)
        w2v[hi] = *(const f32x4*)(W2 + (size_t)m * HID + w * 64 + hi * 16 + g * 4);
    const float b2v = b2[m];
    const f32x4 zc = (f32x4){0.f, 0.f, 0.f, 0.f};

    // ---- stage tile 0 (linear 12 KB copy; fab is pre-swizzled).
    {
        const char* src = (const char*)(fab + (size_t)row_base * KF);
        char* dst = (char*)&Abuf[0][0];
#pragma unroll
        for (int i = 0; i < 3; ++i)
            gl_lds16(src + (size_t)(t + i * 256) * 16, dst + (t + i * 256) * 16);
    }
    __syncthreads();

    for (int tile = 0; tile < 16; ++tile) {
        const int cur = tile & 1;
        const int r0 = row_base + tile * 32;

        // issue next tile's stage early (drained by this tile's barrier)
        if (tile < 15) {
            const char* src = (const char*)(fab + (size_t)(r0 + 32) * KF);
            char* dst = (char*)&Abuf[cur ^ 1][0];
#pragma unroll
            for (int i = 0; i < 3; ++i)
                gl_lds16(src + (size_t)(t + i * 256) * 16, dst + (t + i * 256) * 16);
        }
        // hoisted skip-connection gather (latency hidden under K-loop)
        float skipv = 0.0f;
        if (t < 32) skipv = f_t[(size_t)(r0 + t) * NF + m];

        f32x4 acc[4][2];   // [hi][bj]
        const char* ab = (const char*)&Abuf[cur][0];

        // ks = 0: C = zero vector (no per-tile acc zero-init VALU)
        {
            bf16x8 a[2];
#pragma unroll
            for (int bj = 0; bj < 2; ++bj) {
                int off = (bj * 16 + lrow) * 384 + ((g * 16) ^ xr);
                a[bj] = *(const bf16x8*)(ab + off);
            }
#pragma unroll
            for (int hi = 0; hi < 4; ++hi)
#pragma unroll
                for (int bj = 0; bj < 2; ++bj)
                    acc[hi][bj] = __builtin_amdgcn_mfma_f32_16x16x32_bf16(
                        bfrag[hi][0], a[bj], zc, 0, 0, 0);
        }
#pragma unroll
        for (int ks = 1; ks < 5; ++ks) {
            bf16x8 a[2];   // fa frag: batch = bj*16 + lrow, k = ks*32 + g*8
#pragma unroll
            for (int bj = 0; bj < 2; ++bj) {
                int off = (bj * 16 + lrow) * 384 + ((ks * 64 + g * 16) ^ xr);
                a[bj] = *(const bf16x8*)(ab + off);
            }
#pragma unroll
            for (int hi = 0; hi < 4; ++hi)
#pragma unroll
                for (int bj = 0; bj < 2; ++bj)
                    acc[hi][bj] = __builtin_amdgcn_mfma_f32_16x16x32_bf16(
                        bfrag[hi][ks], a[bj], acc[hi][bj], 0, 0, 0);
        }

        // ---- epilogue: relu(acc) * W2 (b1 folded into GEMM).
        float sarr[2];
#pragma unroll
        for (int bj = 0; bj < 2; ++bj) {
            float sr0 = 0.f, sr1 = 0.f, sr2 = 0.f, sr3 = 0.f;
#pragma unroll
            for (int hi = 0; hi < 4; ++hi) {
                float h0 = acc[hi][bj][0]; h0 = h0 > 0.f ? h0 : 0.f;
                float h1 = acc[hi][bj][1]; h1 = h1 > 0.f ? h1 : 0.f;
                float h2 = acc[hi][bj][2]; h2 = h2 > 0.f ? h2 : 0.f;
                float h3 = acc[hi][bj][3]; h3 = h3 > 0.f ? h3 : 0.f;
                sr0 = fmaf(h0, w2v[hi][0], sr0);
                sr1 = fmaf(h1, w2v[hi][1], sr1);
                sr2 = fmaf(h2, w2v[hi][2], sr2);
                sr3 = fmaf(h3, w2v[hi][3], sr3);
            }
            float s = (sr0 + sr1) + (sr2 + sr3);
            // sum the 4 g-groups (hid quarters of this wave's 64 cols)
            s += __shfl_xor(s, 16, 64);
            s += __shfl_xor(s, 32, 64);
            sarr[bj] = s;
        }
        // lanes with g<2 store batch row (g&1)*16 + lrow
        if (g < 2)
            partial[cur][w][(g & 1) * 16 + lrow] = (g & 1) ? sarr[1] : sarr[0];

        __syncthreads();   // partial ready; stage(tile+1) drained; Abuf[cur] free
        if (t < 32) {
            float v = (partial[cur][0][t] + partial[cur][1][t])
                    + (partial[cur][2][t] + partial[cur][3][t])
                    + b2v + skipv;
            out[(size_t)(r0 + t) * NF + m] = v;
        }
    }
}

// ---------------------------------------------------------------------------
extern "C" void kernel_launch(void* const* d_in, const int* in_sizes, int n_in,
                              void* d_out, int out_size, void* d_ws, size_t ws_size,
                              hipStream_t stream) {
    const float* f_t = (const float*)d_in[0];
    const float* a_t = (const float*)d_in[1];
    const float* W1  = (const float*)d_in[2];
    const float* b1  = (const float*)d_in[3];
    const float* W2  = (const float*)d_in[4];
    const float* b2  = (const float*)d_in[5];
    float* out = (float*)d_out;

    // ws layout: w1t bf16 [128][256][160] (10.49 MB), fab bf16 [4096][192] (1.57 MB)
    __hip_bfloat16* w1t = (__hip_bfloat16*)d_ws;
    __hip_bfloat16* fab = (__hip_bfloat16*)((char*)d_ws + (size_t)NF * HID * KP * 2);

    // converts merged: 1280 w1t blocks + 384 fa blocks
    hipLaunchKernelGGL(convert_all, dim3(1664), dim3(256), 0, stream,
                       W1, b1, f_t, a_t, w1t, fab);
    hipLaunchKernelGGL(fused_mlp, dim3(1024), dim3(256), 0, stream,
                       fab, w1t, W2, b2, f_t, out);
}